// Round 3
// baseline (1313.533 us; speedup 1.0000x reference)
//
#include <hip/hip_runtime.h>
#include <stdint.h>

#define B_  2048
#define T_  64
#define D_  512
#define S_  256
#define P_  11
#define H1_ 384
#define NG_ 1152   // H1 + 3S
#define KH_ 256

typedef unsigned short ushort_t;
typedef __attribute__((ext_vector_type(4))) float    f32x4;
typedef __attribute__((ext_vector_type(8))) __bf16   bf16x8;
typedef __attribute__((ext_vector_type(8))) unsigned short u16x8;

static __device__ __forceinline__ ushort_t f2bf(float f) {
    uint32_t u = __builtin_bit_cast(uint32_t, f);
    u += 0x7fffu + ((u >> 16) & 1u);
    return (ushort_t)(u >> 16);
}
static __device__ __forceinline__ float bf2f(ushort_t h) {
    uint32_t u = ((uint32_t)h) << 16;
    return __builtin_bit_cast(float, u);
}
static __device__ __forceinline__ u16x8 ntload8(const ushort_t* p) {
    return __builtin_nontemporal_load((const u16x8*)p);
}

// Fragment-major layout (featP / WcatP), shared by convert_feat / pack_weights /
// gemm_pre: per 128x512 tile, the u16x8 chunk id is
//   (((kt*2 + kc)*2 + half)*4 + i)*64 + lane      (8192 chunks per tile)
// holding rows row = half*64 + i*16 + (lane&15), cols kt*64 + kc*32 + (lane>>4)*8 + j.
// A wave's MFMA fragment load is then one fully-coalesced 1KB global_load_dwordx4.

// ---------------------------------------------------------------- convert feat
__global__ __launch_bounds__(256) void convert_feat(
        const float* __restrict__ feat,   // [131072][512], row m = b*64+t
        ushort_t* __restrict__ featP) {   // [1024 mtile][8192 chunks] frag-major
    int base = blockIdx.x * 1024 + threadIdx.x;
    #pragma unroll
    for (int k = 0; k < 4; ++k) {
        int o = base + k * 256;               // u16x8 chunk id, 0..8388607
        int mt = o >> 13;
        int f = o & 8191;
        int ln = f & 63;
        int i = (f >> 6) & 3;
        int half = (f >> 8) & 1;
        int kc = (f >> 9) & 1;
        int kt = f >> 10;
        int row = half * 64 + i * 16 + (ln & 15);
        int col = kt * 64 + kc * 32 + ((ln >> 4) << 3);
        const float* gp = feat + (size_t)(mt * 128 + row) * 512 + col;
        f32x4 f0 = __builtin_nontemporal_load((const f32x4*)gp);
        f32x4 f1 = __builtin_nontemporal_load((const f32x4*)(gp + 4));
        u16x8 ov;
        #pragma unroll
        for (int j = 0; j < 4; ++j) { ov[j] = f2bf(f0[j]); ov[4 + j] = f2bf(f1[j]); }
        __builtin_nontemporal_store(ov, (u16x8*)(featP + (size_t)o * 8));
    }
}

// ---------------------------------------------------------------- pack weights
// WcatP: frag-major tiles [9 ntile][8192] of [W1[:, :512] ; Wih[:, :512]]
// WhBp : fragment-packed  [72 nt][8 kc][64 lane][8] of [W1[:,512:768] ; Whh]
__global__ void pack_weights(const float* __restrict__ W1,   // [384][768]
                             const float* __restrict__ Wih,  // [768][513]
                             const float* __restrict__ Whh,  // [768][256]
                             ushort_t* __restrict__ WcatP,
                             ushort_t* __restrict__ WhBp) {
    int idx = blockIdx.x * 256 + threadIdx.x;
    const int tot1 = NG_ * D_;                 // 589824
    if (idx < tot1) {
        int o = idx >> 3, j = idx & 7;
        int ntile = o >> 13;                   // 0..8
        int f = o & 8191;
        int ln = f & 63;
        int i = (f >> 6) & 3;
        int half = (f >> 8) & 1;
        int kc = (f >> 9) & 1;
        int kt = f >> 10;
        int row = half * 64 + i * 16 + (ln & 15);
        int col = kt * 64 + kc * 32 + ((ln >> 4) << 3) + j;
        int n = ntile * 128 + row;
        float v = (n < H1_) ? W1[n * 768 + col] : Wih[(n - H1_) * 513 + col];
        WcatP[idx] = f2bf(v);
    } else {
        int i = idx - tot1;                    // < 294912
        int j  = i & 7;
        int l  = (i >> 3) & 63;
        int kc = (i >> 9) & 7;
        int nt = i >> 12;                      // 0..71
        int row = nt * 16 + (l & 15);
        int col = kc * 32 + (l >> 4) * 8 + j;
        float v = (row < H1_) ? W1[row * 768 + 512 + col] : Whh[(row - H1_) * 256 + col];
        WhBp[i] = f2bf(v);
    }
}

// ---------------------------------------------------------------- phase A GEMM
// pre[m][n] = sum_k feat[m][k] * Wcat[n][k]   (bf16 out, fp32 accum), m = b*64+t
// No LDS, no barriers: both operands stream from L2 as coalesced fragment loads.
__global__ __launch_bounds__(256, 3) void gemm_pre(
        const ushort_t* __restrict__ featP,  // [1024][8192] frag-major
        const ushort_t* __restrict__ WcatP,  // [9][8192] frag-major
        ushort_t* __restrict__ pre) {        // [131072][1152]
    int bx = blockIdx.x;              // 9216 blocks
    int xcd = bx & 7, slt = bx >> 3;
    int mt = (slt / 9) * 8 + xcd;     // 0..1023
    int ntb = slt % 9;                // 0..8
    int m0 = mt * 128, n0 = ntb * 128;

    int tid = threadIdx.x;
    int lane = tid & 63, wave = tid >> 6;
    int wr = wave >> 1, wc = wave & 1;
    int l15 = lane & 15, q = lane >> 4;

    const ushort_t* Ab = featP + ((size_t)mt << 16) + (size_t)(lane << 3);
    const ushort_t* Bb = WcatP + ((size_t)ntb << 16) + (size_t)(lane << 3);

    f32x4 acc[4][4];
    #pragma unroll
    for (int i = 0; i < 4; ++i)
        #pragma unroll
        for (int j = 0; j < 4; ++j)
            acc[i][j] = (f32x4){0.f, 0.f, 0.f, 0.f};

    #pragma unroll
    for (int kt = 0; kt < 8; ++kt) {
        #pragma unroll
        for (int kc = 0; kc < 2; ++kc) {
            bf16x8 af[4], bfr[4];
            #pragma unroll
            for (int i = 0; i < 4; ++i)
                af[i] = __builtin_bit_cast(bf16x8, *(const u16x8*)(
                    Ab + ((((kt * 2 + kc) * 2 + wr) * 4 + i) << 9)));
            #pragma unroll
            for (int j = 0; j < 4; ++j)
                bfr[j] = __builtin_bit_cast(bf16x8, *(const u16x8*)(
                    Bb + ((((kt * 2 + kc) * 2 + wc) * 4 + j) << 9)));
            #pragma unroll
            for (int i = 0; i < 4; ++i)
                #pragma unroll
                for (int j = 0; j < 4; ++j)
                    acc[i][j] = __builtin_amdgcn_mfma_f32_16x16x32_bf16(
                        af[i], bfr[j], acc[i][j], 0, 0, 0);
        }
    }
    #pragma unroll
    for (int i = 0; i < 4; ++i) {
        #pragma unroll
        for (int r = 0; r < 4; ++r) {
            int m = m0 + wr * 64 + i * 16 + q * 4 + r;
            ushort_t* op = pre + (size_t)m * NG_ + n0 + wc * 64 + l15;
            #pragma unroll
            for (int j = 0; j < 4; ++j)
                __builtin_nontemporal_store(f2bf(acc[i][j][r]), &op[j * 16]);
        }
    }
}

// ---------------------------------------------------------------- phase B: recurrence
// 256 blocks x 1024 threads; block owns 8 batch rows, loops t=0..63.
// 3 barriers/step: B1 (hidb ready), B4 (pos+gates ready), B5 (h + next preg ready).
// relu fused into part-1 producer waves; preg/u double-buffered (commit overlaps GRU).
__global__ __launch_bounds__(1024, 4) void recurrent(
        const float* __restrict__ u,       // [2048][64][11]
        const float* __restrict__ b1,      // [384]
        const float* __restrict__ W2,      // [11][384]
        const float* __restrict__ b2,      // [11]
        const float* __restrict__ temp_p,  // [1]
        const float* __restrict__ Wih,     // [768][513] (col 512 = w_pos)
        const float* __restrict__ bih,     // [768]
        const float* __restrict__ bhh,     // [768]
        const float* __restrict__ h0,      // [256]
        const ushort_t* __restrict__ WhBp, // fragment-packed [72][8][64][8] bf16
        const ushort_t* __restrict__ pre,  // [131072][1152] bf16, row m=b*64+t
        float* __restrict__ out_pos,       // [2048][64]
        float* __restrict__ out_states,    // [2048][64][256]
        float* __restrict__ out_hfin) {    // [2048][256]
    // all 2D strides chosen so stride%32 dwords == 4 (no power-of-2 bank aliasing)
    __shared__ __attribute__((aligned(16))) ushort_t gates[8][776];     // part-2 only
    __shared__ __attribute__((aligned(16))) ushort_t preg[2][8][1160];  // double-buffered
    __shared__ __attribute__((aligned(16))) float    hf[8][256];
    __shared__ __attribute__((aligned(16))) ushort_t hb[16][264];       // rows 8..15 zero
    __shared__ __attribute__((aligned(16))) ushort_t hidb[16][392];     // rows 8..15 zero
    __shared__ __attribute__((aligned(16))) ushort_t w2s[16][392];      // rows 11..15 zero
    __shared__ __attribute__((aligned(16))) float    b1s[384];
    __shared__ __attribute__((aligned(16))) float    wps[768];
    __shared__ __attribute__((aligned(16))) float    bihs[768];
    __shared__ __attribute__((aligned(16))) float    bhhs[768];
    __shared__ float    b2s[16];
    __shared__ float    logit_s[8][17];
    __shared__ float    pos_s[8];
    __shared__ float    u_s[2][8][12];

    const int tid  = threadIdx.x;
    const int lane = tid & 63, wave = tid >> 6;       // 16 waves
    const int l15  = lane & 15, q = lane >> 4;
    const int row8 = tid >> 7;                        // elementwise row 0..7
    const int ln128 = tid & 127;                      // elementwise lane 0..127
    const int b0 = blockIdx.x * 8;

    // ---------------- one-time init ----------------
    for (int i = tid; i < 384; i += 1024) b1s[i] = b1[i];
    for (int i = tid; i < 768; i += 1024) {
        wps[i]  = Wih[i * 513 + 512];
        bihs[i] = bih[i];
        bhhs[i] = bhh[i];
    }
    if (tid < 11) b2s[tid] = b2[tid];
    for (int i = tid; i < 16 * 392; i += 1024) {
        int r = i / 392, c = i - r * 392;
        float v = (r < 11 && c < 384) ? W2[r * 384 + c] : 0.f;
        w2s[r][c] = f2bf(v);
    }
    for (int i = tid; i < 8 * 256; i += 1024) {
        int m = i >> 8, s = i & 255;
        float v = h0[s];
        hf[m][s] = v;
        hb[m][s] = f2bf(v);
    }
    for (int i = tid; i < 8 * 264; i += 1024) {      // zero hb rows 8..15
        int m = 8 + i / 264;
        hb[m][i % 264] = 0;
    }
    for (int i = tid; i < 8 * 392; i += 1024) {      // zero hidb rows 8..15
        int m = 8 + i / 392;
        hidb[m][i % 392] = 0;
    }
    float tinv = 1.0f / temp_p[0];

    // ---------------- prologue: stage t=0 pre rows + u into buffer 0 ----------------
    const int um = tid / 11, up = tid - um * 11;     // for tid < 88
    u16x8 pr[2];
    {
        #pragma unroll
        for (int r = 0; r < 2; ++r) {
            int c = tid + (r << 10);
            if (c < 1152) {
                int row = c / 144, off = c - row * 144;
                pr[r] = ntload8(pre + ((size_t)(b0 + row) * 64 + 0) * NG_ + (size_t)off * 8);
            }
        }
        #pragma unroll
        for (int r = 0; r < 2; ++r) {
            int c = tid + (r << 10);
            if (c < 1152) {
                int row = c / 144, off = c - row * 144;
                *(u16x8*)&preg[0][row][off * 8] = pr[r];
            }
        }
        if (tid < 88) u_s[0][um][up] = u[((size_t)(b0 + um) * 64 + 0) * 11 + up];
    }
    __syncthreads();

    for (int t = 0; t < 64; ++t) {
        const int cur = t & 1, nxt = cur ^ 1;

        // A-fragments of h (written by previous step's GRU phase, visible after B5)
        bf16x8 af[8];
        #pragma unroll
        for (int kc = 0; kc < 8; ++kc)
            af[kc] = __builtin_bit_cast(bf16x8, *(const u16x8*)&hb[l15][kc * 32 + q * 8]);

        auto mfma_tile = [&](int nt) -> f32x4 {
            const ushort_t* wp = WhBp + ((size_t)nt << 12) + (lane << 3);
            f32x4 acc = (f32x4){0.f, 0.f, 0.f, 0.f};
            #pragma unroll
            for (int kc = 0; kc < 8; ++kc) {
                bf16x8 bfr = __builtin_bit_cast(bf16x8, *(const u16x8*)(wp + (kc << 9)));
                acc = __builtin_amdgcn_mfma_f32_16x16x32_bf16(af[kc], bfr, acc, 0, 0, 0);
            }
            return acc;
        };
        auto do_relu = [&](int nt) {   // part-1 tile: fused bias+pre+relu -> hidb
            f32x4 acc = mfma_tile(nt);
            if (q < 2) {
                int n = nt * 16 + l15;
                #pragma unroll
                for (int r = 0; r < 4; ++r) {
                    int row = q * 4 + r;
                    float v = acc[r] + bf2f(preg[cur][row][n]) + b1s[n];
                    hidb[row][n] = f2bf(fmaxf(v, 0.f));
                }
            }
        };
        auto do_gates = [&](int nt) {  // part-2 tile -> gates (cols 384.. -> local 0..)
            f32x4 acc = mfma_tile(nt);
            if (q < 2) {
                int n = (nt - 24) * 16 + l15;
                #pragma unroll
                for (int r = 0; r < 4; ++r)
                    gates[q * 4 + r][n] = f2bf(acc[r]);
            }
        };

        // -------- part-1 tiles (0..23): fused relu --------
        if (wave == 0) {
            do_relu(0); do_relu(1); do_relu(2);
        } else {
            int nt = 3 + (wave - 1);
            do_relu(nt);
            nt += 15;
            if (nt < 24) do_relu(nt);
        }
        __syncthreads();                                   // B1: hidb complete

        if (wave == 0) {
            // logits MFMA + in-wave softmax (overlaps other waves' part-2 GEMM)
            f32x4 lacc = (f32x4){0.f, 0.f, 0.f, 0.f};
            #pragma unroll
            for (int kc = 0; kc < 12; ++kc) {
                bf16x8 ha = __builtin_bit_cast(bf16x8,
                    *(const u16x8*)&hidb[l15][kc * 32 + q * 8]);
                bf16x8 wb = __builtin_bit_cast(bf16x8,
                    *(const u16x8*)&w2s[l15][kc * 32 + q * 8]);
                lacc = __builtin_amdgcn_mfma_f32_16x16x32_bf16(ha, wb, lacc, 0, 0, 0);
            }
            if (q < 2) {
                #pragma unroll
                for (int r = 0; r < 4; ++r)
                    logit_s[q * 4 + r][l15] = lacc[r];
            }
            __builtin_amdgcn_s_waitcnt(0);   // drain own LDS writes, then in-wave read
            if (lane < 8) {
                int m = lane;
                float lg[11];
                float mx = -1e30f;
                #pragma unroll
                for (int p = 0; p < 11; ++p) {
                    float uu = u_s[cur][m][p];
                    float g = -__logf(-__logf(uu + 1e-20f) + 1e-20f);
                    float a = (logit_s[m][p] + b2s[p] + g) * tinv;
                    lg[p] = a;
                    mx = fmaxf(mx, a);
                }
                float se = 0.f, sp = 0.f;
                #pragma unroll
                for (int p = 0; p < 11; ++p) {
                    float e = __expf(lg[p] - mx);
                    se += e;
                    sp += e * (float)p;
                }
                float pos = sp / se;
                pos_s[m] = pos;
                __builtin_nontemporal_store(pos, &out_pos[(size_t)(b0 + m) * 64 + t]);
            }
        } else {
            // -------- part-2 tiles (24..71) --------
            int nt = 3 + (wave - 1) + 15;
            while (nt < 24) nt += 15;
            for (; nt < 72; nt += 15) do_gates(nt);
        }

        // prefetch next step's pre rows + u (committed during GRU phase below)
        float uval = 0.f;
        if (t < 63) {
            #pragma unroll
            for (int r = 0; r < 2; ++r) {
                int c = tid + (r << 10);
                if (c < 1152) {
                    int row = c / 144, off = c - row * 144;
                    pr[r] = ntload8(pre + ((size_t)(b0 + row) * 64 + (t + 1)) * NG_
                                    + (size_t)off * 8);
                }
            }
            if (tid < 88) uval = u[((size_t)(b0 + um) * 64 + (t + 1)) * 11 + up];
        }
        __syncthreads();                                   // B4: pos + gates visible

        // GRU update (reads preg[cur] + gates), then commit t+1 into preg[nxt]
        {
            float pos = pos_s[row8];
            float* st = out_states + ((size_t)(b0 + row8) * 64 + t) * 256;
            #pragma unroll
            for (int j = 0; j < 2; ++j) {
                int s = ln128 + (j << 7);
                float ar  = bf2f(preg[cur][row8][384 + s]) + bihs[s]
                          + bf2f(gates[row8][s]) + bhhs[s];
                float az  = bf2f(preg[cur][row8][640 + s]) + bihs[256 + s]
                          + bf2f(gates[row8][256 + s]) + bhhs[256 + s];
                float in0 = bf2f(preg[cur][row8][896 + s]) + bihs[512 + s];
                float gn  = bf2f(gates[row8][512 + s]) + bhhs[512 + s];
                float hp  = hf[row8][s];
                float rr = __builtin_amdgcn_rcpf(1.f + __expf(-(ar + pos * wps[s])));
                float zz = __builtin_amdgcn_rcpf(1.f + __expf(-(az + pos * wps[256 + s])));
                float xn = in0 + pos * wps[512 + s] + rr * gn;
                float e2 = __expf(2.f * xn);
                float nn = 1.f - 2.f * __builtin_amdgcn_rcpf(e2 + 1.f);
                float hnew = (1.f - zz) * nn + zz * hp;
                hf[row8][s] = hnew;
                hb[row8][s] = f2bf(hnew);
                __builtin_nontemporal_store(hnew, st + s);
            }
            if (t < 63) {
                #pragma unroll
                for (int r = 0; r < 2; ++r) {
                    int c = tid + (r << 10);
                    if (c < 1152) {
                        int row = c / 144, off = c - row * 144;
                        *(u16x8*)&preg[nxt][row][off * 8] = pr[r];
                    }
                }
                if (tid < 88) u_s[nxt][um][up] = uval;
            }
        }
        __syncthreads();                                   // B5
    }

    for (int i = tid; i < 8 * 256; i += 1024) {
        int m = i >> 8, s = i & 255;
        __builtin_nontemporal_store(hf[m][s], &out_hfin[(size_t)(b0 + m) * 256 + s]);
    }
}

// ---------------------------------------------------------------- launch
extern "C" void kernel_launch(void* const* d_in, const int* in_sizes, int n_in,
                              void* d_out, int out_size, void* d_ws, size_t ws_size,
                              hipStream_t stream) {
    const float* feat = (const float*)d_in[0];
    const float* u    = (const float*)d_in[1];
    const float* W1   = (const float*)d_in[2];
    const float* b1   = (const float*)d_in[3];
    const float* W2   = (const float*)d_in[4];
    const float* b2   = (const float*)d_in[5];
    const float* temp = (const float*)d_in[6];
    const float* Wih  = (const float*)d_in[7];
    const float* bih  = (const float*)d_in[8];
    const float* Whh  = (const float*)d_in[9];
    const float* bhh  = (const float*)d_in[10];
    const float* h0   = (const float*)d_in[11];

    ushort_t* WcatP = (ushort_t*)d_ws;             // [9][8192]*8 frag-major
    ushort_t* WhBp  = WcatP + NG_ * D_;            // [72][8][64][8] packed
    ushort_t* pre   = WhBp + NG_ * KH_;            // [131072][1152]
    ushort_t* featP = pre + (size_t)T_ * B_ * NG_; // [1024][8192]*8 frag-major

    float* out_pos    = (float*)d_out;
    float* out_states = out_pos + (size_t)B_ * T_;
    float* out_hfin   = out_states + (size_t)B_ * T_ * S_;

    pack_weights<<<3456, 256, 0, stream>>>(W1, Wih, Whh, WcatP, WhBp);
    convert_feat<<<8192, 256, 0, stream>>>(feat, featP);
    gemm_pre<<<9216, 256, 0, stream>>>(featP, WcatP, pre);
    recurrent<<<256, 1024, 0, stream>>>(u, b1, W2, b2, temp, Wih, bih, bhh, h0,
                                        WhBp, pre, out_pos, out_states, out_hfin);
}